// Round 10
// baseline (363.249 us; speedup 1.0000x reference)
//
#include <hip/hip_runtime.h>

// Mandelbrot counts — R6-proven bit-exact arithmetic + compaction + wave-
// aggregated enqueue (R8) + packed fp32 fused z-block (R14) + 8px/lane
// stage A and 2-strip ladder (R18).
//
// R17 post-mortem: harness-level crash, no data. R17's one risky construct
// was inline asm with a VALU-written SGPR pair read by the NEXT SALU inst
// (v_cmp -> s_and_b64) — a hazard class where inline asm must self-insert
// wait states; withdrawn. Bookkeeping reverts to the PROVEN C form.
//
// Cross-round ledger (R12=234.8/5n/2px-strips, R14=237.6/3n/fixed-240,
// R16=239.0/5n/4px-strips) is only consistent with ~15-25us per dispatch
// boundary -> minimize nodes x B-compute jointly:
//   R18 = 4 nodes: memset + A(8px/lane, 16 checks) + B1(16..85, q0->q1)
//         + B2(86..255, finish).  B checks 239M vs 461M fixed-240.
// 8px/lane A halves wave count -> halves per-wave prologue/enqueue overhead
// and doubles ILP across the pk chains; VGPR ~56 (still 8 waves/SIMD).
//
// Proven bit-exact sequence per check (absmax=0 lineage R6..R16):
//   zi2=fl(zi*zi); mag=fma(zr,zr,zi2); t=fma(zr,zr,-zi2)  [VOP3P neg mod]
//   zr'=fl(t+cr); t2=fl(zr+zr); zi'=fma(t2,zi,ci)
//   act=(mag<4)?act:0 (sticky, NaN-safe); cnt+=act (exact small-int add)
// Cardioid/bulb shortcut margin 1e-3 (HW-validated).
//
// d_ws: [0,4096) 64 lines x 64B; line s dwords +0=q0 cnt, +4=q1 cnt.
// q0 recs @4096 (float4 seg-major, idx after), q1 after q0. Overflow at any
// enqueue -> finish inline (correct, slower). ws too small for 2 queues ->
// single-queue fixed-240 path; tiny ws -> monolithic fallback.

#define MAX_ITERS 256

typedef __attribute__((ext_vector_type(2))) float f32x2;
typedef __attribute__((ext_vector_type(4))) float f32x4;

// ---------- scalar proven body (fallback + overflow inline) ----------
__device__ __forceinline__ float mul32(float a, float b) {
    float d; asm("v_mul_f32 %0, %1, %2" : "=v"(d) : "v"(a), "v"(b)); return d;
}
__device__ __forceinline__ float add32(float a, float b) {
    float d; asm("v_add_f32 %0, %1, %2" : "=v"(d) : "v"(a), "v"(b)); return d;
}
__device__ __forceinline__ float fma32(float a, float b, float c) {
    float d; asm("v_fma_f32 %0, %1, %2, %3" : "=v"(d) : "v"(a), "v"(b), "v"(c)); return d;
}
__device__ __forceinline__ float fma32_negc(float a, float b, float c) {
    float d; asm("v_fma_f32 %0, %1, %2, -%3" : "=v"(d) : "v"(a), "v"(b), "v"(c)); return d;
}

__device__ __forceinline__ void iter_checks(float cr, float ci,
                                            float& zr, float& zi,
                                            float& act, float& cnt, int nchecks)
{
    #pragma unroll 8
    for (int s = 0; s < nchecks; ++s) {
        const float zi2 = mul32(zi, zi);
        const float mag = fma32(zr, zr, zi2);
        act = (mag < 4.0f) ? act : 0.0f;
        cnt = cnt + act;
        const float t   = fma32_negc(zr, zr, zi2);
        const float nr  = add32(t, cr);
        const float t2  = add32(zr, zr);
        zi = fma32(t2, zi, ci);
        zr = nr;
    }
}

// ---------- fused packed z-step: exactly 6 v_pk ops, mag out ----------
__device__ __forceinline__ void zstep2(const f32x2 cr, const f32x2 ci,
                                       f32x2& zr, f32x2& zi, f32x2& mag)
{
    f32x2 s, t, u;
    asm("v_pk_mul_f32 %0, %5, %5\n\t"                                   // s   = zi*zi
        "v_pk_fma_f32 %1, %4, %4, %0\n\t"                               // mag = zr*zr + s
        "v_pk_fma_f32 %2, %4, %4, %0 neg_lo:[0,0,1] neg_hi:[0,0,1]\n\t" // t = zr*zr - s
        "v_pk_add_f32 %3, %4, %4\n\t"                                   // u   = zr + zr
        "v_pk_add_f32 %4, %2, %6\n\t"                                   // zr' = t + cr
        "v_pk_fma_f32 %5, %3, %5, %7"                                   // zi' = u*zi + ci
        : "=&v"(s), "=&v"(mag), "=&v"(t), "=&v"(u), "+v"(zr), "+v"(zi)
        : "v"(cr), "v"(ci));
}

// One check over 4 pixels (two streams). Bookkeeping is the PROVEN C form.
__device__ __forceinline__ void check4(
    const f32x2 crA, const f32x2 ciA, f32x2& zrA, f32x2& ziA,
    const f32x2 crB, const f32x2 ciB, f32x2& zrB, f32x2& ziB,
    float& act0, float& act1, float& act2, float& act3,
    float& cnt0, float& cnt1, float& cnt2, float& cnt3)
{
    f32x2 magA, magB;
    zstep2(crA, ciA, zrA, ziA, magA);
    zstep2(crB, ciB, zrB, ziB, magB);
    act0 = (magA.x < 4.0f) ? act0 : 0.0f;  cnt0 += act0;
    act1 = (magA.y < 4.0f) ? act1 : 0.0f;  cnt1 += act1;
    act2 = (magB.x < 4.0f) ? act2 : 0.0f;  cnt2 += act2;
    act3 = (magB.y < 4.0f) ? act3 : 0.0f;  cnt3 += act3;
}

__device__ __forceinline__ int lane_id() {
    return __builtin_amdgcn_mbcnt_hi(~0u, __builtin_amdgcn_mbcnt_lo(~0u, 0));
}

__device__ __forceinline__ bool in_shortcut(float cr, float ci) {
    const float xq = cr - 0.25f;
    const float q  = xq * xq + ci * ci;
    const bool in_card = (q * (q + xq) - 0.25f * ci * ci) < -1e-3f;
    const float xb = cr + 1.0f;
    const bool in_bulb = (xb * xb + ci * ci) < (0.0625f - 1e-3f);
    return in_card | in_bulb;
}

// ---------- stage A: 8 pixels per thread, 16 checks, enqueue to q0 ----------
__global__ __launch_bounds__(256) void mandel_stage_a_o(
    const float* __restrict__ c_real, const float* __restrict__ c_imag,
    float* __restrict__ out, unsigned char* __restrict__ ws,
    unsigned seg_cap, int n)
{
    const int to = blockIdx.x * blockDim.x + threadIdx.x;
    const int p0 = to << 3;
    if (p0 >= n) return;

    if (p0 + 7 >= n) {  // ragged tail: finish fully inline, proven scalar
        for (int j = 0; j < 8 && p0 + j < n; ++j) {
            const float cr = c_real[p0 + j], ci = c_imag[p0 + j];
            if (in_shortcut(cr, ci)) { out[p0 + j] = 256.0f; continue; }
            float zr = cr, zi = ci, act = 1.0f, cnt = 0.0f;
            iter_checks(cr, ci, zr, zi, act, cnt, MAX_ITERS);
            out[p0 + j] = cnt;
        }
        return;
    }

    const f32x4 crL = *(const f32x4*)(c_real + p0);
    const f32x4 crH = *(const f32x4*)(c_real + p0 + 4);
    const f32x4 ciL = *(const f32x4*)(c_imag + p0);
    const f32x4 ciH = *(const f32x4*)(c_imag + p0 + 4);
    const f32x2 crA = {crL.x, crL.y}, crB = {crL.z, crL.w};
    const f32x2 crC = {crH.x, crH.y}, crD = {crH.z, crH.w};
    const f32x2 ciA = {ciL.x, ciL.y}, ciB = {ciL.z, ciL.w};
    const f32x2 ciC = {ciH.x, ciH.y}, ciD = {ciH.z, ciH.w};

    const bool sc[8] = {
        in_shortcut(crA.x, ciA.x), in_shortcut(crA.y, ciA.y),
        in_shortcut(crB.x, ciB.x), in_shortcut(crB.y, ciB.y),
        in_shortcut(crC.x, ciC.x), in_shortcut(crC.y, ciC.y),
        in_shortcut(crD.x, ciD.x), in_shortcut(crD.y, ciD.y)};

    f32x2 zrA = crA, ziA = ciA, zrB = crB, ziB = ciB;
    f32x2 zrC = crC, ziC = ciC, zrD = crD, ziD = ciD;
    float a0 = 1.0f, a1 = 1.0f, a2 = 1.0f, a3 = 1.0f;
    float a4 = 1.0f, a5 = 1.0f, a6 = 1.0f, a7 = 1.0f;
    float n0 = 0.0f, n1 = 0.0f, n2 = 0.0f, n3 = 0.0f;
    float n4 = 0.0f, n5 = 0.0f, n6 = 0.0f, n7 = 0.0f;

    #pragma unroll
    for (int it = 0; it < 16; ++it) {   // checks z_0..z_15
        check4(crA, ciA, zrA, ziA, crB, ciB, zrB, ziB,
               a0, a1, a2, a3, n0, n1, n2, n3);
        check4(crC, ciC, zrC, ziC, crD, ciD, zrD, ziD,
               a4, a5, a6, a7, n4, n5, n6, n7);
    }

    const float av[8] = {a0, a1, a2, a3, a4, a5, a6, a7};
    const float nv[8] = {n0, n1, n2, n3, n4, n5, n6, n7};
    bool sv[8];
    #pragma unroll
    for (int j = 0; j < 8; ++j) sv[j] = (!sc[j]) && (av[j] != 0.0f);

    unsigned long long mv[8];
    unsigned long long any = 0ull;
    #pragma unroll
    for (int j = 0; j < 8; ++j) { mv[j] = __ballot(sv[j]); any |= mv[j]; }

    const int lane = lane_id();
    if (any != 0ull) {
        const int leader = (int)__ffsll(any) - 1;
        const int seg = blockIdx.x & 63;
        unsigned* ctr = (unsigned*)(ws + (size_t)seg * 64u);
        unsigned prev[8], tot = 0u;
        #pragma unroll
        for (int j = 0; j < 8; ++j) {
            prev[j] = tot; tot += (unsigned)__popcll(mv[j]);
        }
        unsigned base = 0u;
        if (lane == leader) base = atomicAdd(ctr, tot);
        base = (unsigned)__shfl((int)base, leader, 64);
        float4* qf = (float4*)(ws + 4096);
        int*    qi = (int*)(ws + 4096 + (size_t)seg_cap * 64u * 16u);
        const unsigned long long below = (1ull << lane) - 1ull;
        const size_t segbase = (size_t)seg * seg_cap;

        const float zrv[8] = {zrA.x, zrA.y, zrB.x, zrB.y,
                              zrC.x, zrC.y, zrD.x, zrD.y};
        const float ziv[8] = {ziA.x, ziA.y, ziB.x, ziB.y,
                              ziC.x, ziC.y, ziD.x, ziD.y};
        const float crv[8] = {crA.x, crA.y, crB.x, crB.y,
                              crC.x, crC.y, crD.x, crD.y};
        const float civ[8] = {ciA.x, ciA.y, ciB.x, ciB.y,
                              ciC.x, ciC.y, ciD.x, ciD.y};
        #pragma unroll
        for (int j = 0; j < 8; ++j) {
            if (!sv[j]) continue;
            const unsigned slot = base + prev[j] +
                (unsigned)__popcll(mv[j] & below);
            if (slot < seg_cap) {
                qf[segbase + slot] = make_float4(zrv[j], ziv[j], crv[j], civ[j]);
                qi[segbase + slot] = p0 + j;
            } else {   // overflow: finish inline with proven scalar body
                float zrs = zrv[j], zis = ziv[j], as = 1.0f, cs = nv[j];
                iter_checks(crv[j], civ[j], zrs, zis, as, cs, 240);
                out[p0 + j] = cs;
            }
        }
    }
    // epilogue: pixels not enqueued (escaped in 0..15, or shortcut)
    #pragma unroll
    for (int j = 0; j < 8; ++j)
        if (!sv[j]) out[p0 + j] = sc[j] ? 256.0f : nv[j];
}

// ---------- strip: NCHECKS on 4 records/thread, optional requeue ----------
template <int NCHECKS, int START, bool HAS_DST>
__global__ __launch_bounds__(256) void mandel_strip_q(
    float* __restrict__ out, unsigned char* __restrict__ ws,
    const float4* __restrict__ srcF, const int* __restrict__ srcI,
    float4* __restrict__ dstF, int* __restrict__ dstI,
    int src_ctr, int dst_ctr, unsigned seg_cap, int blocks_per_seg)
{
    const int seg = (int)(blockIdx.x & 63u);
    const int grp = (int)(blockIdx.x >> 6);
    const unsigned cnt_s = __hip_atomic_load(
        (const unsigned*)(ws + (size_t)seg * 64u + (size_t)src_ctr * 4u),
        __ATOMIC_RELAXED, __HIP_MEMORY_SCOPE_AGENT);
    const unsigned nq = (cnt_s < seg_cap) ? cnt_s : seg_cap;
    const unsigned q = (nq + 3u) >> 2;
    const unsigned stride = (unsigned)blocks_per_seg * 256u;
    const size_t segbase = (size_t)seg * seg_cap;
    const int lane = lane_id();

    for (unsigned k = (unsigned)grp * 256u + threadIdx.x; k < q; k += stride) {
        const unsigned i1 = k + q, i2 = k + 2u * q, i3 = k + 3u * q;
        const bool v1 = (i1 < nq), v2 = (i2 < nq), v3 = (i3 < nq);
        const float4 r0 = srcF[segbase + k];
        const float4 r1 = v1 ? srcF[segbase + i1] : r0;
        const float4 r2 = v2 ? srcF[segbase + i2] : r0;
        const float4 r3 = v3 ? srcF[segbase + i3] : r0;
        const int idx0 = srcI[segbase + k];
        const int idx1 = v1 ? srcI[segbase + i1] : -1;
        const int idx2 = v2 ? srcI[segbase + i2] : -1;
        const int idx3 = v3 ? srcI[segbase + i3] : -1;

        f32x2 zrA = {r0.x, r1.x}, ziA = {r0.y, r1.y};
        f32x2 crA = {r0.z, r1.z}, ciA = {r0.w, r1.w};
        f32x2 zrB = {r2.x, r3.x}, ziB = {r2.y, r3.y};
        f32x2 crB = {r2.z, r3.z}, ciB = {r2.w, r3.w};
        float act0 = 1.0f, act1 = v1 ? 1.0f : 0.0f;
        float act2 = v2 ? 1.0f : 0.0f, act3 = v3 ? 1.0f : 0.0f;
        float cnt0 = (float)START, cnt1 = (float)START;
        float cnt2 = (float)START, cnt3 = (float)START;
        #pragma unroll 8
        for (int s = 0; s < NCHECKS; ++s)
            check4(crA, ciA, zrA, ziA, crB, ciB, zrB, ziB,
                   act0, act1, act2, act3, cnt0, cnt1, cnt2, cnt3);

        if (HAS_DST) {
            const bool sv0 = (act0 != 0.0f);
            const bool sv1 = (act1 != 0.0f);   // invalid halves stay dead
            const bool sv2 = (act2 != 0.0f);
            const bool sv3 = (act3 != 0.0f);
            const unsigned long long m0 = __ballot(sv0);
            const unsigned long long m1 = __ballot(sv1);
            const unsigned long long m2 = __ballot(sv2);
            const unsigned long long m3 = __ballot(sv3);
            const unsigned long long any = m0 | m1 | m2 | m3;
            if (any != 0ull) {
                const int leader = (int)__ffsll(any) - 1;
                unsigned* ctr = (unsigned*)(ws + (size_t)seg * 64u
                                               + (size_t)dst_ctr * 4u);
                const unsigned c0 = (unsigned)__popcll(m0);
                const unsigned c1 = (unsigned)__popcll(m1);
                const unsigned c2 = (unsigned)__popcll(m2);
                unsigned base = 0u;
                if (lane == leader)
                    base = atomicAdd(ctr, c0 + c1 + c2 + (unsigned)__popcll(m3));
                base = (unsigned)__shfl((int)base, leader, 64);
                const unsigned long long below = (1ull << lane) - 1ull;

                const float zrv[4] = {zrA.x, zrA.y, zrB.x, zrB.y};
                const float ziv[4] = {ziA.x, ziA.y, ziB.x, ziB.y};
                const float crv[4] = {crA.x, crA.y, crB.x, crB.y};
                const float civ[4] = {ciA.x, ciA.y, ciB.x, ciB.y};
                const float cnv[4] = {cnt0, cnt1, cnt2, cnt3};
                const int  idxv[4] = {idx0, idx1, idx2, idx3};
                const bool svv[4] = {sv0, sv1, sv2, sv3};
                const unsigned prev[4] = {0u, c0, c0 + c1, c0 + c1 + c2};
                const unsigned long long mvv[4] = {m0, m1, m2, m3};
                #pragma unroll
                for (int j = 0; j < 4; ++j) {
                    if (!svv[j]) continue;
                    const unsigned slot = base + prev[j] +
                        (unsigned)__popcll(mvv[j] & below);
                    if (slot < seg_cap) {
                        dstF[segbase + slot] =
                            make_float4(zrv[j], ziv[j], crv[j], civ[j]);
                        dstI[segbase + slot] = idxv[j];
                    } else {   // overflow: finish inline (correct, slower)
                        float zrs = zrv[j], zis = ziv[j], as = 1.0f, cs = cnv[j];
                        iter_checks(crv[j], civ[j], zrs, zis, as, cs,
                                    256 - START - NCHECKS);
                        out[idxv[j]] = cs;
                    }
                }
            }
            if (!sv0) out[idx0] = cnt0;          // escaped this strip
            if (v1 && !sv1) out[idx1] = cnt1;
            if (v2 && !sv2) out[idx2] = cnt2;
            if (v3 && !sv3) out[idx3] = cnt3;
        } else {
            out[idx0] = cnt0;                    // final strip
            if (v1) out[idx1] = cnt1;
            if (v2) out[idx2] = cnt2;
            if (v3) out[idx3] = cnt3;
        }
    }
}

// ---------- proven scalar fallback (tiny ws only) ----------
__global__ __launch_bounds__(256) void mandel_mono(
    const float* __restrict__ c_real, const float* __restrict__ c_imag,
    float* __restrict__ out, int n)
{
    int i = blockIdx.x * blockDim.x + threadIdx.x;
    if (i >= n) return;
    const float cr = c_real[i], ci = c_imag[i];
    float zr = cr, zi = ci, act = 1.0f, cnt = 0.0f;
    iter_checks(cr, ci, zr, zi, act, cnt, MAX_ITERS);
    out[i] = cnt;
}

extern "C" void kernel_launch(void* const* d_in, const int* in_sizes, int n_in,
                              void* d_out, int out_size, void* d_ws, size_t ws_size,
                              hipStream_t stream)
{
    const float* c_real = (const float*)d_in[0];
    const float* c_imag = (const float*)d_in[1];
    float* out = (float*)d_out;
    const int n = in_sizes[0];  // 4096*4096
    const int block = 256;

    unsigned char* ws = (unsigned char*)d_ws;
    const size_t avail = (ws_size > 4096) ? (ws_size - 4096) : 0;
    const unsigned seg_cap1 = (unsigned)(avail / (64u * 20u));        // 1 queue
    const unsigned seg_cap2 = (unsigned)(avail / (64u * 20u * 2u));   // 2 queues

    if (seg_cap1 < 8192u) {  // ws too small for compaction: proven fallback
        const int gridA = (n + block - 1) / block;
        mandel_mono<<<gridA, block, 0, stream>>>(c_real, c_imag, out, n);
        return;
    }

    // zero the 64 counter lines (graph-legal async memset, no extra kernel)
    hipMemsetAsync(ws, 0, 4096, stream);

    const int nocts = (n + 7) / 8;
    const int gridA = (nocts + block - 1) / block;

    if (seg_cap2 >= 33000u) {
        // 2-strip ladder with ping-pong queues (4 graph nodes total).
        const unsigned sc = seg_cap2;
        float4* q0f = (float4*)(ws + 4096);
        int*    q0i = (int*)(ws + 4096 + (size_t)sc * 64u * 16u);
        float4* q1f = (float4*)(ws + 4096 + (size_t)sc * 64u * 20u);
        int*    q1i = (int*)(ws + 4096 + (size_t)sc * 64u * 20u
                                       + (size_t)sc * 64u * 16u);

        mandel_stage_a_o<<<gridA, block, 0, stream>>>(c_real, c_imag, out,
                                                      ws, sc, n);
        // B1: checks 16..85 (70), q0 -> q1 (ctr 0 -> ctr 1)
        mandel_strip_q<70, 16, true><<<64 * 32, block, 0, stream>>>(
            out, ws, q0f, q0i, q1f, q1i, 0, 1, sc, 32);
        // B2: checks 86..255 (170), finish (ctr 1)
        mandel_strip_q<170, 86, false><<<64 * 16, block, 0, stream>>>(
            out, ws, q1f, q1i, (float4*)nullptr, (int*)nullptr, 1, 0, sc, 16);
        return;
    }

    // Single-queue path: stage A + fixed-240 stage B.
    mandel_stage_a_o<<<gridA, block, 0, stream>>>(c_real, c_imag, out,
                                                  ws, seg_cap1, n);
    mandel_strip_q<240, 16, false><<<64 * 32, block, 0, stream>>>(
        out, ws,
        (const float4*)(ws + 4096),
        (const int*)(ws + 4096 + (size_t)seg_cap1 * 64u * 16u),
        (float4*)nullptr, (int*)nullptr, 0, 0, seg_cap1, 32);
}

// Round 11
// 253.531 us; speedup vs baseline: 1.4328x; 1.4328x over previous
//
#include <hip/hip_runtime.h>

// Mandelbrot counts — R6-proven bit-exact arithmetic + compaction + wave-
// aggregated enqueue (R8) + packed fp32 fused z-block (R14) + 8px/lane
// stage A (R18) + 3-strip ladder with EXPLICIT occupancy bounds (R19).
//
// R18 post-mortem (363us regression): strip kernels compiled to VGPR=256,
// occupancy 8.6%, VALUBusy 0.1-11%, WRITE_SIZE +35MB = SCRATCH SPILL — the
// 70/170-check template instantiations crossed a regalloc heuristic and the
// compiler took the whole 256-VGPR budget (no __launch_bounds__ minimum
// given). Strips became latency-bound spill loops (174+144us vs ~25us
// datapath floor). Fix: __launch_bounds__(256, 4) (cap 128 VGPR, 4 waves/
// SIMD guaranteed) on ALL iteration kernels + revert to the R16-proven
// 40/80/120 instantiations. Stage A 8px/lane was NOT in the top-5 slowest
// dispatches (all strips) -> it is fast; kept.
//
// Proven bit-exact sequence per check (absmax=0 lineage R6..R18):
//   zi2=fl(zi*zi); mag=fma(zr,zr,zi2); t=fma(zr,zr,-zi2)  [VOP3P neg mod]
//   zr'=fl(t+cr); t2=fl(zr+zr); zi'=fma(t2,zi,ci)
//   act=(mag<4)?act:0 (sticky, NaN-safe); cnt+=act (exact small-int add)
// Cardioid/bulb shortcut margin 1e-3 (HW-validated).
//
// Ladder: A: checks 0..15 (all px, 8px/lane) -> q0 | B1: 16..55 q0->q1 |
// B2: 56..135 q1->q0 storage | B3: 136..255 finish. Counters: 64 lines x
// 64B, dwords +0/+4/+8. Overflow -> finish inline (correct, slower).
// ws too small for 2 queues -> single-queue fixed-240; tiny ws -> mono.

#define MAX_ITERS 256

typedef __attribute__((ext_vector_type(2))) float f32x2;
typedef __attribute__((ext_vector_type(4))) float f32x4;

// ---------- scalar proven body (fallback + overflow inline) ----------
__device__ __forceinline__ float mul32(float a, float b) {
    float d; asm("v_mul_f32 %0, %1, %2" : "=v"(d) : "v"(a), "v"(b)); return d;
}
__device__ __forceinline__ float add32(float a, float b) {
    float d; asm("v_add_f32 %0, %1, %2" : "=v"(d) : "v"(a), "v"(b)); return d;
}
__device__ __forceinline__ float fma32(float a, float b, float c) {
    float d; asm("v_fma_f32 %0, %1, %2, %3" : "=v"(d) : "v"(a), "v"(b), "v"(c)); return d;
}
__device__ __forceinline__ float fma32_negc(float a, float b, float c) {
    float d; asm("v_fma_f32 %0, %1, %2, -%3" : "=v"(d) : "v"(a), "v"(b), "v"(c)); return d;
}

__device__ __forceinline__ void iter_checks(float cr, float ci,
                                            float& zr, float& zi,
                                            float& act, float& cnt, int nchecks)
{
    #pragma unroll 8
    for (int s = 0; s < nchecks; ++s) {
        const float zi2 = mul32(zi, zi);
        const float mag = fma32(zr, zr, zi2);
        act = (mag < 4.0f) ? act : 0.0f;
        cnt = cnt + act;
        const float t   = fma32_negc(zr, zr, zi2);
        const float nr  = add32(t, cr);
        const float t2  = add32(zr, zr);
        zi = fma32(t2, zi, ci);
        zr = nr;
    }
}

// ---------- fused packed z-step: exactly 6 v_pk ops, mag out ----------
__device__ __forceinline__ void zstep2(const f32x2 cr, const f32x2 ci,
                                       f32x2& zr, f32x2& zi, f32x2& mag)
{
    f32x2 s, t, u;
    asm("v_pk_mul_f32 %0, %5, %5\n\t"                                   // s   = zi*zi
        "v_pk_fma_f32 %1, %4, %4, %0\n\t"                               // mag = zr*zr + s
        "v_pk_fma_f32 %2, %4, %4, %0 neg_lo:[0,0,1] neg_hi:[0,0,1]\n\t" // t = zr*zr - s
        "v_pk_add_f32 %3, %4, %4\n\t"                                   // u   = zr + zr
        "v_pk_add_f32 %4, %2, %6\n\t"                                   // zr' = t + cr
        "v_pk_fma_f32 %5, %3, %5, %7"                                   // zi' = u*zi + ci
        : "=&v"(s), "=&v"(mag), "=&v"(t), "=&v"(u), "+v"(zr), "+v"(zi)
        : "v"(cr), "v"(ci));
}

// One check over 4 pixels (two streams). Bookkeeping is the PROVEN C form.
__device__ __forceinline__ void check4(
    const f32x2 crA, const f32x2 ciA, f32x2& zrA, f32x2& ziA,
    const f32x2 crB, const f32x2 ciB, f32x2& zrB, f32x2& ziB,
    float& act0, float& act1, float& act2, float& act3,
    float& cnt0, float& cnt1, float& cnt2, float& cnt3)
{
    f32x2 magA, magB;
    zstep2(crA, ciA, zrA, ziA, magA);
    zstep2(crB, ciB, zrB, ziB, magB);
    act0 = (magA.x < 4.0f) ? act0 : 0.0f;  cnt0 += act0;
    act1 = (magA.y < 4.0f) ? act1 : 0.0f;  cnt1 += act1;
    act2 = (magB.x < 4.0f) ? act2 : 0.0f;  cnt2 += act2;
    act3 = (magB.y < 4.0f) ? act3 : 0.0f;  cnt3 += act3;
}

__device__ __forceinline__ int lane_id() {
    return __builtin_amdgcn_mbcnt_hi(~0u, __builtin_amdgcn_mbcnt_lo(~0u, 0));
}

__device__ __forceinline__ bool in_shortcut(float cr, float ci) {
    const float xq = cr - 0.25f;
    const float q  = xq * xq + ci * ci;
    const bool in_card = (q * (q + xq) - 0.25f * ci * ci) < -1e-3f;
    const float xb = cr + 1.0f;
    const bool in_bulb = (xb * xb + ci * ci) < (0.0625f - 1e-3f);
    return in_card | in_bulb;
}

// ---------- stage A: 8 pixels per thread, 16 checks, enqueue to q0 ----------
__global__ __launch_bounds__(256, 4) void mandel_stage_a_o(
    const float* __restrict__ c_real, const float* __restrict__ c_imag,
    float* __restrict__ out, unsigned char* __restrict__ ws,
    unsigned seg_cap, int n)
{
    const int to = blockIdx.x * blockDim.x + threadIdx.x;
    const int p0 = to << 3;
    if (p0 >= n) return;

    if (p0 + 7 >= n) {  // ragged tail: finish fully inline, proven scalar
        for (int j = 0; j < 8 && p0 + j < n; ++j) {
            const float cr = c_real[p0 + j], ci = c_imag[p0 + j];
            if (in_shortcut(cr, ci)) { out[p0 + j] = 256.0f; continue; }
            float zr = cr, zi = ci, act = 1.0f, cnt = 0.0f;
            iter_checks(cr, ci, zr, zi, act, cnt, MAX_ITERS);
            out[p0 + j] = cnt;
        }
        return;
    }

    const f32x4 crL = *(const f32x4*)(c_real + p0);
    const f32x4 crH = *(const f32x4*)(c_real + p0 + 4);
    const f32x4 ciL = *(const f32x4*)(c_imag + p0);
    const f32x4 ciH = *(const f32x4*)(c_imag + p0 + 4);
    const f32x2 crA = {crL.x, crL.y}, crB = {crL.z, crL.w};
    const f32x2 crC = {crH.x, crH.y}, crD = {crH.z, crH.w};
    const f32x2 ciA = {ciL.x, ciL.y}, ciB = {ciL.z, ciL.w};
    const f32x2 ciC = {ciH.x, ciH.y}, ciD = {ciH.z, ciH.w};

    const bool sc[8] = {
        in_shortcut(crA.x, ciA.x), in_shortcut(crA.y, ciA.y),
        in_shortcut(crB.x, ciB.x), in_shortcut(crB.y, ciB.y),
        in_shortcut(crC.x, ciC.x), in_shortcut(crC.y, ciC.y),
        in_shortcut(crD.x, ciD.x), in_shortcut(crD.y, ciD.y)};

    f32x2 zrA = crA, ziA = ciA, zrB = crB, ziB = ciB;
    f32x2 zrC = crC, ziC = ciC, zrD = crD, ziD = ciD;
    float a0 = 1.0f, a1 = 1.0f, a2 = 1.0f, a3 = 1.0f;
    float a4 = 1.0f, a5 = 1.0f, a6 = 1.0f, a7 = 1.0f;
    float n0 = 0.0f, n1 = 0.0f, n2 = 0.0f, n3 = 0.0f;
    float n4 = 0.0f, n5 = 0.0f, n6 = 0.0f, n7 = 0.0f;

    #pragma unroll
    for (int it = 0; it < 16; ++it) {   // checks z_0..z_15
        check4(crA, ciA, zrA, ziA, crB, ciB, zrB, ziB,
               a0, a1, a2, a3, n0, n1, n2, n3);
        check4(crC, ciC, zrC, ziC, crD, ciD, zrD, ziD,
               a4, a5, a6, a7, n4, n5, n6, n7);
    }

    const float av[8] = {a0, a1, a2, a3, a4, a5, a6, a7};
    const float nv[8] = {n0, n1, n2, n3, n4, n5, n6, n7};
    bool sv[8];
    #pragma unroll
    for (int j = 0; j < 8; ++j) sv[j] = (!sc[j]) && (av[j] != 0.0f);

    unsigned long long mv[8];
    unsigned long long any = 0ull;
    #pragma unroll
    for (int j = 0; j < 8; ++j) { mv[j] = __ballot(sv[j]); any |= mv[j]; }

    const int lane = lane_id();
    if (any != 0ull) {
        const int leader = (int)__ffsll(any) - 1;
        const int seg = blockIdx.x & 63;
        unsigned* ctr = (unsigned*)(ws + (size_t)seg * 64u);
        unsigned prev[8], tot = 0u;
        #pragma unroll
        for (int j = 0; j < 8; ++j) {
            prev[j] = tot; tot += (unsigned)__popcll(mv[j]);
        }
        unsigned base = 0u;
        if (lane == leader) base = atomicAdd(ctr, tot);
        base = (unsigned)__shfl((int)base, leader, 64);
        float4* qf = (float4*)(ws + 4096);
        int*    qi = (int*)(ws + 4096 + (size_t)seg_cap * 64u * 16u);
        const unsigned long long below = (1ull << lane) - 1ull;
        const size_t segbase = (size_t)seg * seg_cap;

        const float zrv[8] = {zrA.x, zrA.y, zrB.x, zrB.y,
                              zrC.x, zrC.y, zrD.x, zrD.y};
        const float ziv[8] = {ziA.x, ziA.y, ziB.x, ziB.y,
                              ziC.x, ziC.y, ziD.x, ziD.y};
        const float crv[8] = {crA.x, crA.y, crB.x, crB.y,
                              crC.x, crC.y, crD.x, crD.y};
        const float civ[8] = {ciA.x, ciA.y, ciB.x, ciB.y,
                              ciC.x, ciC.y, ciD.x, ciD.y};
        #pragma unroll
        for (int j = 0; j < 8; ++j) {
            if (!sv[j]) continue;
            const unsigned slot = base + prev[j] +
                (unsigned)__popcll(mv[j] & below);
            if (slot < seg_cap) {
                qf[segbase + slot] = make_float4(zrv[j], ziv[j], crv[j], civ[j]);
                qi[segbase + slot] = p0 + j;
            } else {   // overflow: finish inline with proven scalar body
                float zrs = zrv[j], zis = ziv[j], as = 1.0f, cs = nv[j];
                iter_checks(crv[j], civ[j], zrs, zis, as, cs, 240);
                out[p0 + j] = cs;
            }
        }
    }
    // epilogue: pixels not enqueued (escaped in 0..15, or shortcut)
    #pragma unroll
    for (int j = 0; j < 8; ++j)
        if (!sv[j]) out[p0 + j] = sc[j] ? 256.0f : nv[j];
}

// ---------- strip: NCHECKS on 4 records/thread, optional requeue ----------
// __launch_bounds__(256, 4): cap 128 VGPR (R18's 256-VGPR spill fix).
template <int NCHECKS, int START, bool HAS_DST>
__global__ __launch_bounds__(256, 4) void mandel_strip_q(
    float* __restrict__ out, unsigned char* __restrict__ ws,
    const float4* __restrict__ srcF, const int* __restrict__ srcI,
    float4* __restrict__ dstF, int* __restrict__ dstI,
    int src_ctr, int dst_ctr, unsigned seg_cap, int blocks_per_seg)
{
    const int seg = (int)(blockIdx.x & 63u);
    const int grp = (int)(blockIdx.x >> 6);
    const unsigned cnt_s = __hip_atomic_load(
        (const unsigned*)(ws + (size_t)seg * 64u + (size_t)src_ctr * 4u),
        __ATOMIC_RELAXED, __HIP_MEMORY_SCOPE_AGENT);
    const unsigned nq = (cnt_s < seg_cap) ? cnt_s : seg_cap;
    const unsigned q = (nq + 3u) >> 2;
    const unsigned stride = (unsigned)blocks_per_seg * 256u;
    const size_t segbase = (size_t)seg * seg_cap;
    const int lane = lane_id();

    for (unsigned k = (unsigned)grp * 256u + threadIdx.x; k < q; k += stride) {
        const unsigned i1 = k + q, i2 = k + 2u * q, i3 = k + 3u * q;
        const bool v1 = (i1 < nq), v2 = (i2 < nq), v3 = (i3 < nq);
        const float4 r0 = srcF[segbase + k];
        const float4 r1 = v1 ? srcF[segbase + i1] : r0;
        const float4 r2 = v2 ? srcF[segbase + i2] : r0;
        const float4 r3 = v3 ? srcF[segbase + i3] : r0;
        const int idx0 = srcI[segbase + k];
        const int idx1 = v1 ? srcI[segbase + i1] : -1;
        const int idx2 = v2 ? srcI[segbase + i2] : -1;
        const int idx3 = v3 ? srcI[segbase + i3] : -1;

        f32x2 zrA = {r0.x, r1.x}, ziA = {r0.y, r1.y};
        f32x2 crA = {r0.z, r1.z}, ciA = {r0.w, r1.w};
        f32x2 zrB = {r2.x, r3.x}, ziB = {r2.y, r3.y};
        f32x2 crB = {r2.z, r3.z}, ciB = {r2.w, r3.w};
        float act0 = 1.0f, act1 = v1 ? 1.0f : 0.0f;
        float act2 = v2 ? 1.0f : 0.0f, act3 = v3 ? 1.0f : 0.0f;
        float cnt0 = (float)START, cnt1 = (float)START;
        float cnt2 = (float)START, cnt3 = (float)START;
        #pragma unroll 8
        for (int s = 0; s < NCHECKS; ++s)
            check4(crA, ciA, zrA, ziA, crB, ciB, zrB, ziB,
                   act0, act1, act2, act3, cnt0, cnt1, cnt2, cnt3);

        if (HAS_DST) {
            const bool sv0 = (act0 != 0.0f);
            const bool sv1 = (act1 != 0.0f);   // invalid halves stay dead
            const bool sv2 = (act2 != 0.0f);
            const bool sv3 = (act3 != 0.0f);
            const unsigned long long m0 = __ballot(sv0);
            const unsigned long long m1 = __ballot(sv1);
            const unsigned long long m2 = __ballot(sv2);
            const unsigned long long m3 = __ballot(sv3);
            const unsigned long long any = m0 | m1 | m2 | m3;
            if (any != 0ull) {
                const int leader = (int)__ffsll(any) - 1;
                unsigned* ctr = (unsigned*)(ws + (size_t)seg * 64u
                                               + (size_t)dst_ctr * 4u);
                const unsigned c0 = (unsigned)__popcll(m0);
                const unsigned c1 = (unsigned)__popcll(m1);
                const unsigned c2 = (unsigned)__popcll(m2);
                unsigned base = 0u;
                if (lane == leader)
                    base = atomicAdd(ctr, c0 + c1 + c2 + (unsigned)__popcll(m3));
                base = (unsigned)__shfl((int)base, leader, 64);
                const unsigned long long below = (1ull << lane) - 1ull;

                const float zrv[4] = {zrA.x, zrA.y, zrB.x, zrB.y};
                const float ziv[4] = {ziA.x, ziA.y, ziB.x, ziB.y};
                const float crv[4] = {crA.x, crA.y, crB.x, crB.y};
                const float civ[4] = {ciA.x, ciA.y, ciB.x, ciB.y};
                const float cnv[4] = {cnt0, cnt1, cnt2, cnt3};
                const int  idxv[4] = {idx0, idx1, idx2, idx3};
                const bool svv[4] = {sv0, sv1, sv2, sv3};
                const unsigned prev[4] = {0u, c0, c0 + c1, c0 + c1 + c2};
                const unsigned long long mvv[4] = {m0, m1, m2, m3};
                #pragma unroll
                for (int j = 0; j < 4; ++j) {
                    if (!svv[j]) continue;
                    const unsigned slot = base + prev[j] +
                        (unsigned)__popcll(mvv[j] & below);
                    if (slot < seg_cap) {
                        dstF[segbase + slot] =
                            make_float4(zrv[j], ziv[j], crv[j], civ[j]);
                        dstI[segbase + slot] = idxv[j];
                    } else {   // overflow: finish inline (correct, slower)
                        float zrs = zrv[j], zis = ziv[j], as = 1.0f, cs = cnv[j];
                        iter_checks(crv[j], civ[j], zrs, zis, as, cs,
                                    256 - START - NCHECKS);
                        out[idxv[j]] = cs;
                    }
                }
            }
            if (!sv0) out[idx0] = cnt0;          // escaped this strip
            if (v1 && !sv1) out[idx1] = cnt1;
            if (v2 && !sv2) out[idx2] = cnt2;
            if (v3 && !sv3) out[idx3] = cnt3;
        } else {
            out[idx0] = cnt0;                    // final strip
            if (v1) out[idx1] = cnt1;
            if (v2) out[idx2] = cnt2;
            if (v3) out[idx3] = cnt3;
        }
    }
}

// ---------- proven scalar fallback (tiny ws only) ----------
__global__ __launch_bounds__(256) void mandel_mono(
    const float* __restrict__ c_real, const float* __restrict__ c_imag,
    float* __restrict__ out, int n)
{
    int i = blockIdx.x * blockDim.x + threadIdx.x;
    if (i >= n) return;
    const float cr = c_real[i], ci = c_imag[i];
    float zr = cr, zi = ci, act = 1.0f, cnt = 0.0f;
    iter_checks(cr, ci, zr, zi, act, cnt, MAX_ITERS);
    out[i] = cnt;
}

extern "C" void kernel_launch(void* const* d_in, const int* in_sizes, int n_in,
                              void* d_out, int out_size, void* d_ws, size_t ws_size,
                              hipStream_t stream)
{
    const float* c_real = (const float*)d_in[0];
    const float* c_imag = (const float*)d_in[1];
    float* out = (float*)d_out;
    const int n = in_sizes[0];  // 4096*4096
    const int block = 256;

    unsigned char* ws = (unsigned char*)d_ws;
    const size_t avail = (ws_size > 4096) ? (ws_size - 4096) : 0;
    const unsigned seg_cap1 = (unsigned)(avail / (64u * 20u));        // 1 queue
    const unsigned seg_cap2 = (unsigned)(avail / (64u * 20u * 2u));   // 2 queues

    if (seg_cap1 < 8192u) {  // ws too small for compaction: proven fallback
        const int gridA = (n + block - 1) / block;
        mandel_mono<<<gridA, block, 0, stream>>>(c_real, c_imag, out, n);
        return;
    }

    // zero the 64 counter lines (graph-legal async memset, no extra kernel)
    hipMemsetAsync(ws, 0, 4096, stream);

    const int nocts = (n + 7) / 8;
    const int gridA = (nocts + block - 1) / block;

    if (seg_cap2 >= 33000u) {
        // 3-strip ladder (R16-proven instantiations) with ping-pong queues.
        const unsigned sc = seg_cap2;
        float4* q0f = (float4*)(ws + 4096);
        int*    q0i = (int*)(ws + 4096 + (size_t)sc * 64u * 16u);
        float4* q1f = (float4*)(ws + 4096 + (size_t)sc * 64u * 20u);
        int*    q1i = (int*)(ws + 4096 + (size_t)sc * 64u * 20u
                                       + (size_t)sc * 64u * 16u);

        mandel_stage_a_o<<<gridA, block, 0, stream>>>(c_real, c_imag, out,
                                                      ws, sc, n);
        // B1: checks 16..55 (40), q0 -> q1 (ctr 0 -> ctr 1)
        mandel_strip_q<40, 16, true><<<64 * 32, block, 0, stream>>>(
            out, ws, q0f, q0i, q1f, q1i, 0, 1, sc, 32);
        // B2: checks 56..135 (80), q1 -> q0 storage (ctr 1 -> ctr 2)
        mandel_strip_q<80, 56, true><<<64 * 16, block, 0, stream>>>(
            out, ws, q1f, q1i, q0f, q0i, 1, 2, sc, 16);
        // B3: checks 136..255 (120), finish (ctr 2)
        mandel_strip_q<120, 136, false><<<64 * 16, block, 0, stream>>>(
            out, ws, q0f, q0i, (float4*)nullptr, (int*)nullptr, 2, 0, sc, 16);
        return;
    }

    // Single-queue path: stage A + fixed-240 stage B.
    mandel_stage_a_o<<<gridA, block, 0, stream>>>(c_real, c_imag, out,
                                                  ws, seg_cap1, n);
    mandel_strip_q<240, 16, false><<<64 * 32, block, 0, stream>>>(
        out, ws,
        (const float4*)(ws + 4096),
        (const int*)(ws + 4096 + (size_t)seg_cap1 * 64u * 16u),
        (float4*)nullptr, (int*)nullptr, 0, 0, seg_cap1, 32);
}